// Round 17
// baseline (149.359 us; speedup 1.0000x reference)
//
#include <hip/hip_runtime.h>
#include <hip/hip_bf16.h>

#define NROW 8192
#define FIN  512
#define FOUT 64
#define NHEAD 4

constexpr float LOG2E = 1.44269504088896f;

typedef float f32x4 __attribute__((ext_vector_type(4)));
typedef float f32x16 __attribute__((ext_vector_type(16)));
typedef int   i32x4 __attribute__((ext_vector_type(4)));
typedef unsigned u32x4 __attribute__((ext_vector_type(4)));
typedef __bf16 bf16x8 __attribute__((ext_vector_type(8)));
typedef _Float16 f16x8 __attribute__((ext_vector_type(8)));
typedef _Float16 f16x4 __attribute__((ext_vector_type(4)));

// ---------------------------------------------------------------------------
// K0: WT[hd][o][f] = bf16(W[hd][f][o])
// ---------------------------------------------------------------------------
__global__ __launch_bounds__(256) void wt_build(
    const float* __restrict__ W, __hip_bfloat16* __restrict__ WT)
{
  int t = blockIdx.x * 256 + threadIdx.x;
  int hd = t >> 9, f = t & 511;
  const float* wp = W + (hd * FIN + f) * FOUT;
#pragma unroll 8
  for (int o = 0; o < FOUT; ++o)
    WT[(hd * FOUT + o) * FIN + f] = __float2bfloat16(wp[o]);
}

// ---------------------------------------------------------------------------
// K1: h = x*W via MFMA (verified skeleton). Emits hT (f16), f1 (f32),
// E2h = f16 exp2(f2c), D2h = f16 exp2(0.2*f2c).
// ---------------------------------------------------------------------------
__global__ __launch_bounds__(256) void gat_proj(
    const float* __restrict__ x, const __hip_bfloat16* __restrict__ WT,
    const float* __restrict__ a1, const float* __restrict__ a2,
    _Float16* __restrict__ hT, float* __restrict__ f1,
    _Float16* __restrict__ E2h, _Float16* __restrict__ D2h)
{
  const int tid = threadIdx.x;
  const int wid = tid >> 6, lane = tid & 63;
  const int il = lane & 15, kg = lane >> 4;
  const int hd = blockIdx.x & 3;
  const int rg = blockIdx.x >> 2;
  const int n0 = rg * 64;

  __shared__ __align__(16) __hip_bfloat16 wt_lds[64 * 512];   // 64 KB
  __shared__ __align__(16) _Float16 ht_tile[64 * 66];         // 8.25 KB

  {
    const int o = tid >> 2, q = tid & 3;
    const __hip_bfloat16* src = WT + (size_t)(hd * FOUT + o) * FIN;
#pragma unroll
    for (int k = 0; k < 16; ++k) {
      int u = q * 16 + k;
      bf16x8 vv = *(const bf16x8*)(src + u * 8);
      *(bf16x8*)(&wt_lds[o * 512 + (u ^ (o & 7)) * 8]) = vv;
    }
  }
  __syncthreads();

  const int n = n0 + wid * 16 + il;
  const float* xp = x + (size_t)n * FIN + kg * 8;

  f32x4 acc[4];
#pragma unroll
  for (int c = 0; c < 4; ++c) { f32x4 z = {0.f,0.f,0.f,0.f}; acc[c] = z; }

#pragma unroll 4
  for (int kk = 0; kk < FIN / 32; ++kk) {
    f32x4 xl = *(const f32x4*)(xp + kk * 32);
    f32x4 xh = *(const f32x4*)(xp + kk * 32 + 4);
    bf16x8 xb;
#pragma unroll
    for (int e = 0; e < 4; ++e) {
      xb[e]     = (__bf16)xl[e];
      xb[4 + e] = (__bf16)xh[e];
    }
#pragma unroll
    for (int c = 0; c < 4; ++c) {
      const int o = c * 16 + il;
      bf16x8 af = *(const bf16x8*)(
          &wt_lds[o * 512 + ((kk * 4 + kg) ^ (il & 7)) * 8]);
      acc[c] = __builtin_amdgcn_mfma_f32_16x16x32_bf16(af, xb, acc[c], 0, 0, 0);
    }
  }

  float p1 = 0.f, p2 = 0.f;
#pragma unroll
  for (int c = 0; c < 4; ++c) {
    f32x4 a1v = *(const f32x4*)(a1 + hd * FOUT + c * 16 + kg * 4);
    f32x4 a2v = *(const f32x4*)(a2 + hd * FOUT + c * 16 + kg * 4);
#pragma unroll
    for (int r = 0; r < 4; ++r) {
      p1 = fmaf(acc[c][r], a1v[r], p1);
      p2 = fmaf(acc[c][r], a2v[r], p2);
    }
  }
  p1 += __shfl_xor(p1, 16); p1 += __shfl_xor(p1, 32);
  p2 += __shfl_xor(p2, 16); p2 += __shfl_xor(p2, 32);
  if (kg == 0) {
    float f1c = p1 * LOG2E;
    float f2c = p2 * LOG2E;
    f1[hd * NROW + n] = f1c;
    E2h[hd * NROW + n] = (_Float16)__builtin_amdgcn_exp2f(f2c);
    D2h[hd * NROW + n] = (_Float16)__builtin_amdgcn_exp2f(0.2f * f2c);
  }

#pragma unroll
  for (int c = 0; c < 4; ++c)
#pragma unroll
    for (int r = 0; r < 4; ++r)
      ht_tile[(c * 16 + kg * 4 + r) * 66 + wid * 16 + il] =
          (_Float16)acc[c][r];
  __syncthreads();
  {
    const int o = tid >> 2, q = tid & 3;
    f16x8 t0 = *(const f16x8*)(&ht_tile[o * 66 + q * 16]);
    f16x8 t1 = *(const f16x8*)(&ht_tile[o * 66 + q * 16 + 8]);
    _Float16* dst = hT + (size_t)(hd * FOUT + o) * NROW + n0 + q * 16;
    *(f16x8*)(dst)     = t0;
    *(f16x8*)(dst + 8) = t1;
  }
}

// ---------------------------------------------------------------------------
// K3: attention partials — R16 inner loop verbatim (32x32x16 f16 MFMA,
// stride-68 tile, nibble mask dbuf, E|D pair tables, pk-math P-gen,
// 1 barrier/iter), restructured to 512-thread / 8-wave blocks (256 rows)
// with m-split S (8 preferred): 32 waves/CU (100% cap, was 16), barrier
// events per CU halved, per-thread staging halved.
// ---------------------------------------------------------------------------
template <int S>
__global__ __launch_bounds__(512, 4) void gat_attn(
    const int* __restrict__ adj, const _Float16* __restrict__ hTg,
    const float* __restrict__ f1, const _Float16* __restrict__ E2h,
    const _Float16* __restrict__ D2h, float* __restrict__ part)
{
  constexpr int MCH = NROW / S;        // 1024 (S=8)
  constexpr int ITERS = MCH / 64;      // 16
  constexpr int RS = 68;               // tile row stride (f16 elems)
  const int tid = threadIdx.x;
  const int wid = tid >> 6, lane = tid & 63;
  const int jn = lane & 31;            // B j (=n-local) and A i (=o-local)
  const int kg2 = lane >> 5;           // k half-group

  const int nwg = S * NHEAD * (NROW / 256);        // 1024 (S=8)
  const int bid = (blockIdx.x & 7) * (nwg >> 3) + (blockIdx.x >> 3);
  const int hd = bid & 3;
  const int rg = (bid >> 2) & 31;
  const int mc = bid >> 7;
  const int n0 = rg * 256;
  const int n  = n0 + wid * 32 + jn;
  const int mbase = mc * MCH;

  __shared__ __align__(16) _Float16 lds[2][64 * RS];         // 17.4 KB
  __shared__ __align__(16) unsigned tblE[MCH / 2];           // 2 KB (S=8)
  __shared__ __align__(16) unsigned tblD[MCH / 2];           // 2 KB
  __shared__ unsigned char nib[8][2][32][16];                // 8 KB

  const float f1v = f1[hd * NROW + n];
  const float R1f = __builtin_amdgcn_exp2f(-0.8f * f1v);
  const unsigned r1p =
      (unsigned)__builtin_bit_cast(unsigned short, (_Float16)R1f) * 0x10001u;

  const u32x4 shc = {0x000E000Fu, 0x000C000Du, 0x000A000Bu, 0x00080009u};
  const unsigned c15 = 0x000F000Fu;

  // hT tile staging map (512 thr): thread covers row so = tid>>3,
  // cols [sq*8, sq*8+8) -> one f16x8 global load, two f16x4 LDS writes.
  const int so = tid >> 3, sq = tid & 7;
  const _Float16* hs = hTg + (size_t)(hd * FOUT + so) * NROW + mbase + sq * 8;
  const int wbase = so * RS + sq * 8;

  // adj producer: per-wave rows (wid*32 + g*4 + arow), cols acg*4
  const int arow = lane >> 4, acg = lane & 15;
  const int* apn =
      adj + (size_t)(n0 + wid * 32 + arow) * NROW + mbase + acg * 4;

  f32x16 acc0, acc1, accD;
#pragma unroll
  for (int r = 0; r < 16; ++r) { acc0[r] = 0.f; acc1[r] = 0.f; accD[r] = 0.f; }

  f16x8 ones;
#pragma unroll
  for (int e = 0; e < 8; ++e) ones[e] = (_Float16)1.0f;

  // ---- prologue
  i32x4 ld[8];
#pragma unroll
  for (int g = 0; g < 8; ++g)
    ld[g] = *(const i32x4*)(apn + (size_t)(g * 4) * NROW);

  {
    const unsigned* Eg = (const unsigned*)(E2h + hd * NROW + mbase);
    const unsigned* Dg = (const unsigned*)(D2h + hd * NROW + mbase);
    for (int i = tid; i < MCH / 2; i += 512) {
      tblE[i] = Eg[i];
      tblD[i] = Dg[i];
    }
  }
  {
    f16x8 s0 = *(const f16x8*)(hs);
    f16x4 a = {s0[0], s0[1], s0[2], s0[3]};
    f16x4 b = {s0[4], s0[5], s0[6], s0[7]};
    *(f16x4*)(&lds[0][wbase])     = a;
    *(f16x4*)(&lds[0][wbase + 4]) = b;
  }

#pragma unroll
  for (int g = 0; g < 8; ++g) {
    unsigned nv = min((unsigned)ld[g][0], 1u)
                | (min((unsigned)ld[g][1], 1u) << 1)
                | (min((unsigned)ld[g][2], 1u) << 2)
                | (min((unsigned)ld[g][3], 1u) << 3);
    nib[wid][0][g * 4 + arow][acg] = (unsigned char)nv;
  }
#pragma unroll
  for (int g = 0; g < 8; ++g)
    ld[g] = *(const i32x4*)(apn + (size_t)(g * 4) * NROW + 64);

  __syncthreads();

  for (int it = 0; it < ITERS; ++it) {
    const int cur = it & 1, nxt = cur ^ 1;
    const bool more = (it + 1 < ITERS);

    f16x8 s0n;
    if (more)
      s0n = *(const f16x8*)(hs + (it + 1) * 64);

    unsigned short tks[4];
#pragma unroll
    for (int kstep = 0; kstep < 4; ++kstep)
      tks[kstep] =
          *(const unsigned short*)&nib[wid][cur][jn][kstep * 4 + kg2 * 2];

    if (more) {
#pragma unroll
      for (int g = 0; g < 8; ++g) {
        unsigned nv = min((unsigned)ld[g][0], 1u)
                    | (min((unsigned)ld[g][1], 1u) << 1)
                    | (min((unsigned)ld[g][2], 1u) << 2)
                    | (min((unsigned)ld[g][3], 1u) << 3);
        nib[wid][nxt][g * 4 + arow][acg] = (unsigned char)nv;
      }
    }
    if (it + 2 < ITERS) {
#pragma unroll
      for (int g = 0; g < 8; ++g)
        ld[g] = *(const i32x4*)(apn + (size_t)(g * 4) * NROW + (it + 2) * 64);
    }

#pragma unroll
    for (int kstep = 0; kstep < 4; ++kstep) {
      unsigned short tt = tks[kstep];
      unsigned m8 = ((unsigned)tt & 0xFu) | ((((unsigned)tt >> 8) & 0xFu) << 4);
      unsigned w = m8 * 0x10001u;

      const int pbase = it * 32 + kstep * 8 + kg2 * 4;
      u32x4 Ew = *(const u32x4*)(&tblE[pbase]);
      u32x4 Dw = *(const u32x4*)(&tblD[pbase]);

      const int uu = kstep * 2 + kg2;
      const _Float16* t0p = &lds[cur][jn * RS + uu * 8];
      const _Float16* t1p = &lds[cur][(32 + jn) * RS + uu * 8];
      f16x4 lo0 = *(const f16x4*)(t0p);
      f16x4 hi0 = *(const f16x4*)(t0p + 4);
      f16x4 lo1 = *(const f16x4*)(t1p);
      f16x4 hi1 = *(const f16x4*)(t1p + 4);
      f16x8 afr0, afr1;
#pragma unroll
      for (int e = 0; e < 4; ++e) {
        afr0[e] = lo0[e]; afr0[4 + e] = hi0[e];
        afr1[e] = lo1[e]; afr1[4 + e] = hi1[e];
      }

      unsigned qv0, qv1, qv2, qv3;
#pragma unroll
      for (int p = 0; p < 4; ++p) {
        unsigned tmul, qmx, shv, mk;
        asm("v_pk_mul_f16 %0, %1, %2" : "=v"(tmul) : "v"(r1p), "v"(Dw[p]));
        asm("v_pk_max_f16 %0, %1, %2" : "=v"(qmx) : "v"(Ew[p]), "v"(tmul));
        asm("v_pk_lshlrev_b16 %0, %1, %2" : "=v"(shv) : "v"(shc[p]), "v"(w));
        asm("v_pk_ashrrev_i16 %0, %1, %2" : "=v"(mk) : "v"(c15), "v"(shv));
        unsigned q = qmx & mk;
        if (p == 0) qv0 = q; else if (p == 1) qv1 = q;
        else if (p == 2) qv2 = q; else qv3 = q;
      }
      u32x4 qq = {qv0, qv1, qv2, qv3};
      f16x8 pb = __builtin_bit_cast(f16x8, qq);

      acc0 = __builtin_amdgcn_mfma_f32_32x32x16_f16(afr0, pb, acc0, 0, 0, 0);
      acc1 = __builtin_amdgcn_mfma_f32_32x32x16_f16(afr1, pb, acc1, 0, 0, 0);
      accD = __builtin_amdgcn_mfma_f32_32x32x16_f16(ones, pb, accD, 0, 0, 0);
    }

    if (more) {
      f16x4 a = {s0n[0], s0n[1], s0n[2], s0n[3]};
      f16x4 b = {s0n[4], s0n[5], s0n[6], s0n[7]};
      *(f16x4*)(&lds[nxt][wbase])     = a;
      *(f16x4*)(&lds[nxt][wbase + 4]) = b;
      __syncthreads();
    }
  }

  // ---- epilogue: D col = jn (n), row = (reg&3)+8*(reg>>2)+4*kg2 (o-local)
  float* pp = part + ((size_t)((mc * NHEAD + hd) * NROW + n)) * 68;
  const int ob = 4 * kg2;
#pragma unroll
  for (int q = 0; q < 4; ++q) {
    f32x4 v0 = {acc0[q * 4], acc0[q * 4 + 1], acc0[q * 4 + 2], acc0[q * 4 + 3]};
    f32x4 v1 = {acc1[q * 4], acc1[q * 4 + 1], acc1[q * 4 + 2], acc1[q * 4 + 3]};
    *(f32x4*)(pp + q * 8 + ob)      = v0;
    *(f32x4*)(pp + 32 + q * 8 + ob) = v1;
  }
  if (kg2 == 0) pp[64] = accD[0];
}

// ---------------------------------------------------------------------------
// K4: combine S partial slices, divide, sigmoid, write out.
// ---------------------------------------------------------------------------
__global__ __launch_bounds__(256) void gat_comb(
    const float* __restrict__ part, float* __restrict__ out, int S)
{
  int flat = blockIdx.x * 256 + threadIdx.x;
  int n = flat >> 6, c4 = flat & 63;
  int hd = c4 >> 4, o4 = (c4 & 15) * 4;
  f32x4 num = {0.f,0.f,0.f,0.f};
  float L = 0.f;
  for (int s = 0; s < S; ++s) {
    const float* pp = part + ((size_t)((s * NHEAD + hd) * NROW + n)) * 68;
    f32x4 v = *(const f32x4*)(pp + o4);
    num += v;
    L += pp[64];
  }
  float invL = 1.0f / L;
  f32x4 r;
#pragma unroll
  for (int j = 0; j < 4; ++j)
    r[j] = 1.0f / (1.0f + __builtin_amdgcn_exp2f(-num[j] * invL * LOG2E));
  *(f32x4*)(out + (size_t)n * (NHEAD * FOUT) + hd * FOUT + o4) = r;
}

extern "C" void kernel_launch(void* const* d_in, const int* in_sizes, int n_in,
                              void* d_out, int out_size, void* d_ws, size_t ws_size,
                              hipStream_t stream) {
  const float* x   = (const float*)d_in[0];
  const int*   adj = (const int*)d_in[1];
  const float* W   = (const float*)d_in[2];
  const float* a1  = (const float*)d_in[3];
  const float* a2  = (const float*)d_in[4];
  float* out = (float*)d_out;

  char* ws = (char*)d_ws;
  const size_t WT_OFF = 0;
  const size_t HT_OFF = WT_OFF + (size_t)NHEAD * FOUT * FIN * 2;     // 256 KB
  const size_t F1_OFF = HT_OFF + (size_t)NHEAD * FOUT * NROW * 2;    // 4 MB
  const size_t E2_OFF = F1_OFF + (size_t)NHEAD * NROW * 4;           // 128 KB
  const size_t D2_OFF = E2_OFF + (size_t)NHEAD * NROW * 2;           // 64 KB
  const size_t PT_OFF = D2_OFF + (size_t)NHEAD * NROW * 2;           // 64 KB
  const size_t SLICE = (size_t)NHEAD * NROW * 68 * 4;                // 8.9 MB

  int S = (ws_size >= PT_OFF + 8 * SLICE) ? 8
        : (ws_size >= PT_OFF + 4 * SLICE) ? 4 : 2;

  __hip_bfloat16* WT = (__hip_bfloat16*)(ws + WT_OFF);
  _Float16* hT = (_Float16*)(ws + HT_OFF);
  float* f1 = (float*)(ws + F1_OFF);
  _Float16* E2h = (_Float16*)(ws + E2_OFF);
  _Float16* D2h = (_Float16*)(ws + D2_OFF);
  float* part = (float*)(ws + PT_OFF);

  wt_build<<<8, 256, 0, stream>>>(W, WT);
  gat_proj<<<NHEAD * (NROW / 64), 256, 0, stream>>>(x, WT, a1, a2, hT, f1, E2h, D2h);
  if (S == 8)
    gat_attn<8><<<8 * NHEAD * (NROW / 256), 512, 0, stream>>>(
        adj, hT, f1, E2h, D2h, part);
  else if (S == 4)
    gat_attn<4><<<4 * NHEAD * (NROW / 256), 512, 0, stream>>>(
        adj, hT, f1, E2h, D2h, part);
  else
    gat_attn<2><<<2 * NHEAD * (NROW / 256), 512, 0, stream>>>(
        adj, hT, f1, E2h, D2h, part);
  gat_comb<<<NROW * NHEAD * FOUT / 4 / 256, 256, 0, stream>>>(part, out, S);
}

// Round 18
// 128.730 us; speedup vs baseline: 1.1603x; 1.1603x over previous
//
#include <hip/hip_runtime.h>
#include <hip/hip_bf16.h>

#define NROW 8192
#define FIN  512
#define FOUT 64
#define NHEAD 4

constexpr float LOG2E = 1.44269504088896f;

typedef float f32x4 __attribute__((ext_vector_type(4)));
typedef float f32x16 __attribute__((ext_vector_type(16)));
typedef int   i32x4 __attribute__((ext_vector_type(4)));
typedef unsigned u32x4 __attribute__((ext_vector_type(4)));
typedef __bf16 bf16x8 __attribute__((ext_vector_type(8)));
typedef _Float16 f16x8 __attribute__((ext_vector_type(8)));
typedef _Float16 f16x4 __attribute__((ext_vector_type(4)));

// ---------------------------------------------------------------------------
// K0: WT[hd][o][f] = bf16(W[hd][f][o])
// ---------------------------------------------------------------------------
__global__ __launch_bounds__(256) void wt_build(
    const float* __restrict__ W, __hip_bfloat16* __restrict__ WT)
{
  int t = blockIdx.x * 256 + threadIdx.x;
  int hd = t >> 9, f = t & 511;
  const float* wp = W + (hd * FIN + f) * FOUT;
#pragma unroll 8
  for (int o = 0; o < FOUT; ++o)
    WT[(hd * FOUT + o) * FIN + f] = __float2bfloat16(wp[o]);
}

// ---------------------------------------------------------------------------
// K1: h = x*W via MFMA (verified skeleton). Emits hT (f16), f1 (f32),
// E2h = f16 exp2(f2c), D2h = f16 exp2(0.2*f2c).
// ---------------------------------------------------------------------------
__global__ __launch_bounds__(256) void gat_proj(
    const float* __restrict__ x, const __hip_bfloat16* __restrict__ WT,
    const float* __restrict__ a1, const float* __restrict__ a2,
    _Float16* __restrict__ hT, float* __restrict__ f1,
    _Float16* __restrict__ E2h, _Float16* __restrict__ D2h)
{
  const int tid = threadIdx.x;
  const int wid = tid >> 6, lane = tid & 63;
  const int il = lane & 15, kg = lane >> 4;
  const int hd = blockIdx.x & 3;
  const int rg = blockIdx.x >> 2;
  const int n0 = rg * 64;

  __shared__ __align__(16) __hip_bfloat16 wt_lds[64 * 512];   // 64 KB
  __shared__ __align__(16) _Float16 ht_tile[64 * 66];         // 8.25 KB

  {
    const int o = tid >> 2, q = tid & 3;
    const __hip_bfloat16* src = WT + (size_t)(hd * FOUT + o) * FIN;
#pragma unroll
    for (int k = 0; k < 16; ++k) {
      int u = q * 16 + k;
      bf16x8 vv = *(const bf16x8*)(src + u * 8);
      *(bf16x8*)(&wt_lds[o * 512 + (u ^ (o & 7)) * 8]) = vv;
    }
  }
  __syncthreads();

  const int n = n0 + wid * 16 + il;
  const float* xp = x + (size_t)n * FIN + kg * 8;

  f32x4 acc[4];
#pragma unroll
  for (int c = 0; c < 4; ++c) { f32x4 z = {0.f,0.f,0.f,0.f}; acc[c] = z; }

#pragma unroll 4
  for (int kk = 0; kk < FIN / 32; ++kk) {
    f32x4 xl = *(const f32x4*)(xp + kk * 32);
    f32x4 xh = *(const f32x4*)(xp + kk * 32 + 4);
    bf16x8 xb;
#pragma unroll
    for (int e = 0; e < 4; ++e) {
      xb[e]     = (__bf16)xl[e];
      xb[4 + e] = (__bf16)xh[e];
    }
#pragma unroll
    for (int c = 0; c < 4; ++c) {
      const int o = c * 16 + il;
      bf16x8 af = *(const bf16x8*)(
          &wt_lds[o * 512 + ((kk * 4 + kg) ^ (il & 7)) * 8]);
      acc[c] = __builtin_amdgcn_mfma_f32_16x16x32_bf16(af, xb, acc[c], 0, 0, 0);
    }
  }

  float p1 = 0.f, p2 = 0.f;
#pragma unroll
  for (int c = 0; c < 4; ++c) {
    f32x4 a1v = *(const f32x4*)(a1 + hd * FOUT + c * 16 + kg * 4);
    f32x4 a2v = *(const f32x4*)(a2 + hd * FOUT + c * 16 + kg * 4);
#pragma unroll
    for (int r = 0; r < 4; ++r) {
      p1 = fmaf(acc[c][r], a1v[r], p1);
      p2 = fmaf(acc[c][r], a2v[r], p2);
    }
  }
  p1 += __shfl_xor(p1, 16); p1 += __shfl_xor(p1, 32);
  p2 += __shfl_xor(p2, 16); p2 += __shfl_xor(p2, 32);
  if (kg == 0) {
    float f1c = p1 * LOG2E;
    float f2c = p2 * LOG2E;
    f1[hd * NROW + n] = f1c;
    E2h[hd * NROW + n] = (_Float16)__builtin_amdgcn_exp2f(f2c);
    D2h[hd * NROW + n] = (_Float16)__builtin_amdgcn_exp2f(0.2f * f2c);
  }

#pragma unroll
  for (int c = 0; c < 4; ++c)
#pragma unroll
    for (int r = 0; r < 4; ++r)
      ht_tile[(c * 16 + kg * 4 + r) * 66 + wid * 16 + il] =
          (_Float16)acc[c][r];
  __syncthreads();
  {
    const int o = tid >> 2, q = tid & 3;
    f16x8 t0 = *(const f16x8*)(&ht_tile[o * 66 + q * 16]);
    f16x8 t1 = *(const f16x8*)(&ht_tile[o * 66 + q * 16 + 8]);
    _Float16* dst = hT + (size_t)(hd * FOUT + o) * NROW + n0 + q * 16;
    *(f16x8*)(dst)     = t0;
    *(f16x8*)(dst + 8) = t1;
  }
}

// ---------------------------------------------------------------------------
// K3: attention partials — R16 verbatim (32x32x16 f16 MFMA, stride-68 tile,
// nibble mask dbuf, E|D pair tables, pk-math P-gen, 1 barrier/iter) + two
// micros: (a) s_setprio(1) around the P-gen+MFMA cluster (T5; 4 independent
// blocks/CU at different phases = the regime where it paid, m191);
// (b) nib row read as ONE ds_read_b128 + VALU extract (was 4x ds_read_u16,
// same bytes) — 3 fewer ops/iter on the busiest (LDS) pipe.
// ---------------------------------------------------------------------------
__global__ __launch_bounds__(256, 4) void gat_attn(
    const int* __restrict__ adj, const _Float16* __restrict__ hTg,
    const float* __restrict__ f1, const _Float16* __restrict__ E2h,
    const _Float16* __restrict__ D2h, float* __restrict__ part)
{
  constexpr int S = 4;
  constexpr int MCH = NROW / S;        // 2048
  constexpr int ITERS = MCH / 64;      // 32
  constexpr int RS = 68;               // tile row stride (f16 elems)
  const int tid = threadIdx.x;
  const int wid = tid >> 6, lane = tid & 63;
  const int jn = lane & 31;            // B j (=n-local) and A i (=o-local)
  const int kg2 = lane >> 5;           // k half-group

  const int nwg = S * NHEAD * (NROW / 128);        // 1024
  const int bid = (blockIdx.x & 7) * (nwg >> 3) + (blockIdx.x >> 3);
  const int hd = bid & 3;
  const int rg = (bid >> 2) & 63;
  const int mc = bid >> 8;
  const int n0 = rg * 128;
  const int n  = n0 + wid * 32 + jn;
  const int mbase = mc * MCH;

  __shared__ __align__(16) _Float16 lds[2][64 * RS];         // 17.4 KB
  __shared__ __align__(16) unsigned tblE[MCH / 2];           // 4 KB
  __shared__ __align__(16) unsigned tblD[MCH / 2];           // 4 KB
  __shared__ __align__(16) unsigned char nib[NHEAD][2][32][16];  // 4 KB

  const float f1v = f1[hd * NROW + n];
  const float R1f = __builtin_amdgcn_exp2f(-0.8f * f1v);
  const unsigned r1p =
      (unsigned)__builtin_bit_cast(unsigned short, (_Float16)R1f) * 0x10001u;

  const u32x4 shc = {0x000E000Fu, 0x000C000Du, 0x000A000Bu, 0x00080009u};
  const unsigned c15 = 0x000F000Fu;

  // hT tile staging map: thread (so = tid>>2, sq = tid&3) covers row so,
  // cols [sq*16, sq*16+16).
  const int so = tid >> 2, sq = tid & 3;
  const _Float16* hs = hTg + (size_t)(hd * FOUT + so) * NROW + mbase + sq * 16;
  const int wbase = so * RS + sq * 16;

  // adj producer: lane = (row-quarter arow, colgroup acg); rows g*4+arow
  const int arow = lane >> 4, acg = lane & 15;
  const int* apn =
      adj + (size_t)(n0 + wid * 32 + arow) * NROW + mbase + acg * 4;

  f32x16 acc0, acc1, accD;
#pragma unroll
  for (int r = 0; r < 16; ++r) { acc0[r] = 0.f; acc1[r] = 0.f; accD[r] = 0.f; }

  f16x8 ones;
#pragma unroll
  for (int e = 0; e < 8; ++e) ones[e] = (_Float16)1.0f;

  // ---- prologue
  i32x4 ld[8];
#pragma unroll
  for (int g = 0; g < 8; ++g)
    ld[g] = *(const i32x4*)(apn + (size_t)(g * 4) * NROW);

  {
    const unsigned* Eg = (const unsigned*)(E2h + hd * NROW + mbase);
    const unsigned* Dg = (const unsigned*)(D2h + hd * NROW + mbase);
    int idx = tid * 4;
    *(u32x4*)(&tblE[idx]) = *(const u32x4*)(Eg + idx);
    *(u32x4*)(&tblD[idx]) = *(const u32x4*)(Dg + idx);
  }
  {
    f16x8 s0 = *(const f16x8*)(hs);
    f16x8 s1 = *(const f16x8*)(hs + 8);
    f16x4 a = {s0[0], s0[1], s0[2], s0[3]};
    f16x4 b = {s0[4], s0[5], s0[6], s0[7]};
    f16x4 c = {s1[0], s1[1], s1[2], s1[3]};
    f16x4 d = {s1[4], s1[5], s1[6], s1[7]};
    *(f16x4*)(&lds[0][wbase])      = a;
    *(f16x4*)(&lds[0][wbase + 4])  = b;
    *(f16x4*)(&lds[0][wbase + 8])  = c;
    *(f16x4*)(&lds[0][wbase + 12]) = d;
  }

#pragma unroll
  for (int g = 0; g < 8; ++g) {
    unsigned nv = min((unsigned)ld[g][0], 1u)
                | (min((unsigned)ld[g][1], 1u) << 1)
                | (min((unsigned)ld[g][2], 1u) << 2)
                | (min((unsigned)ld[g][3], 1u) << 3);
    nib[wid][0][g * 4 + arow][acg] = (unsigned char)nv;
  }
#pragma unroll
  for (int g = 0; g < 8; ++g)
    ld[g] = *(const i32x4*)(apn + (size_t)(g * 4) * NROW + 64);

  __syncthreads();

  for (int it = 0; it < ITERS; ++it) {
    const int cur = it & 1, nxt = cur ^ 1;
    const bool more = (it + 1 < ITERS);

    f16x8 s0n, s1n;
    if (more) {
      s0n = *(const f16x8*)(hs + (it + 1) * 64);
      s1n = *(const f16x8*)(hs + (it + 1) * 64 + 8);
    }

    // mask row for this iter: ONE b128 read (bytes identical to the old
    // 4x u16 reads; tt(kstep) = u32[kstep] >> (kg2*16) & 0xFFFF)
    u32x4 nr = *(const u32x4*)(&nib[wid][cur][jn][0]);

    if (more) {
#pragma unroll
      for (int g = 0; g < 8; ++g) {
        unsigned nv = min((unsigned)ld[g][0], 1u)
                    | (min((unsigned)ld[g][1], 1u) << 1)
                    | (min((unsigned)ld[g][2], 1u) << 2)
                    | (min((unsigned)ld[g][3], 1u) << 3);
        nib[wid][nxt][g * 4 + arow][acg] = (unsigned char)nv;
      }
    }
    if (it + 2 < ITERS) {
#pragma unroll
      for (int g = 0; g < 8; ++g)
        ld[g] = *(const i32x4*)(apn + (size_t)(g * 4) * NROW + (it + 2) * 64);
    }

    __builtin_amdgcn_s_setprio(1);
#pragma unroll
    for (int kstep = 0; kstep < 4; ++kstep) {
      unsigned tt = (nr[kstep] >> (kg2 * 16)) & 0xFFFFu;
      unsigned m8 = (tt & 0xFu) | (((tt >> 8) & 0xFu) << 4);
      unsigned w = m8 * 0x10001u;

      const int pbase = it * 32 + kstep * 8 + kg2 * 4;
      u32x4 Ew = *(const u32x4*)(&tblE[pbase]);
      u32x4 Dw = *(const u32x4*)(&tblD[pbase]);

      // A-frags: rows jn and 32+jn, elems [uu*8, uu*8+8) at stride RS=68.
      const int uu = kstep * 2 + kg2;
      const _Float16* t0p = &lds[cur][jn * RS + uu * 8];
      const _Float16* t1p = &lds[cur][(32 + jn) * RS + uu * 8];
      f16x4 lo0 = *(const f16x4*)(t0p);
      f16x4 hi0 = *(const f16x4*)(t0p + 4);
      f16x4 lo1 = *(const f16x4*)(t1p);
      f16x4 hi1 = *(const f16x4*)(t1p + 4);
      f16x8 afr0, afr1;
#pragma unroll
      for (int e = 0; e < 4; ++e) {
        afr0[e] = lo0[e]; afr0[4 + e] = hi0[e];
        afr1[e] = lo1[e]; afr1[4 + e] = hi1[e];
      }

      unsigned qv0, qv1, qv2, qv3;
#pragma unroll
      for (int p = 0; p < 4; ++p) {
        unsigned tmul, qmx, shv, mk;
        asm("v_pk_mul_f16 %0, %1, %2" : "=v"(tmul) : "v"(r1p), "v"(Dw[p]));
        asm("v_pk_max_f16 %0, %1, %2" : "=v"(qmx) : "v"(Ew[p]), "v"(tmul));
        asm("v_pk_lshlrev_b16 %0, %1, %2" : "=v"(shv) : "v"(shc[p]), "v"(w));
        asm("v_pk_ashrrev_i16 %0, %1, %2" : "=v"(mk) : "v"(c15), "v"(shv));
        unsigned q = qmx & mk;
        if (p == 0) qv0 = q; else if (p == 1) qv1 = q;
        else if (p == 2) qv2 = q; else qv3 = q;
      }
      u32x4 qq = {qv0, qv1, qv2, qv3};
      f16x8 pb = __builtin_bit_cast(f16x8, qq);

      acc0 = __builtin_amdgcn_mfma_f32_32x32x16_f16(afr0, pb, acc0, 0, 0, 0);
      acc1 = __builtin_amdgcn_mfma_f32_32x32x16_f16(afr1, pb, acc1, 0, 0, 0);
      accD = __builtin_amdgcn_mfma_f32_32x32x16_f16(ones, pb, accD, 0, 0, 0);
    }
    __builtin_amdgcn_s_setprio(0);

    if (more) {
      f16x4 a = {s0n[0], s0n[1], s0n[2], s0n[3]};
      f16x4 b = {s0n[4], s0n[5], s0n[6], s0n[7]};
      f16x4 c = {s1n[0], s1n[1], s1n[2], s1n[3]};
      f16x4 d = {s1n[4], s1n[5], s1n[6], s1n[7]};
      *(f16x4*)(&lds[nxt][wbase])      = a;
      *(f16x4*)(&lds[nxt][wbase + 4])  = b;
      *(f16x4*)(&lds[nxt][wbase + 8])  = c;
      *(f16x4*)(&lds[nxt][wbase + 12]) = d;
      __syncthreads();
    }
  }

  // ---- epilogue: D col = jn (n), row = (reg&3)+8*(reg>>2)+4*kg2 (o-local)
  float* pp = part + ((size_t)((mc * NHEAD + hd) * NROW + n)) * 68;
  const int ob = 4 * kg2;
#pragma unroll
  for (int q = 0; q < 4; ++q) {
    f32x4 v0 = {acc0[q * 4], acc0[q * 4 + 1], acc0[q * 4 + 2], acc0[q * 4 + 3]};
    f32x4 v1 = {acc1[q * 4], acc1[q * 4 + 1], acc1[q * 4 + 2], acc1[q * 4 + 3]};
    *(f32x4*)(pp + q * 8 + ob)      = v0;
    *(f32x4*)(pp + 32 + q * 8 + ob) = v1;
  }
  if (kg2 == 0) pp[64] = accD[0];
}

// ---------------------------------------------------------------------------
// K4: combine S partial slices, divide, sigmoid, write out.
// ---------------------------------------------------------------------------
__global__ __launch_bounds__(256) void gat_comb(
    const float* __restrict__ part, float* __restrict__ out, int S)
{
  int flat = blockIdx.x * 256 + threadIdx.x;
  int n = flat >> 6, c4 = flat & 63;
  int hd = c4 >> 4, o4 = (c4 & 15) * 4;
  f32x4 num = {0.f,0.f,0.f,0.f};
  float L = 0.f;
  for (int s = 0; s < S; ++s) {
    const float* pp = part + ((size_t)((s * NHEAD + hd) * NROW + n)) * 68;
    f32x4 v = *(const f32x4*)(pp + o4);
    num += v;
    L += pp[64];
  }
  float invL = 1.0f / L;
  f32x4 r;
#pragma unroll
  for (int j = 0; j < 4; ++j)
    r[j] = 1.0f / (1.0f + __builtin_amdgcn_exp2f(-num[j] * invL * LOG2E));
  *(f32x4*)(out + (size_t)n * (NHEAD * FOUT) + hd * FOUT + o4) = r;
}

extern "C" void kernel_launch(void* const* d_in, const int* in_sizes, int n_in,
                              void* d_out, int out_size, void* d_ws, size_t ws_size,
                              hipStream_t stream) {
  const float* x   = (const float*)d_in[0];
  const int*   adj = (const int*)d_in[1];
  const float* W   = (const float*)d_in[2];
  const float* a1  = (const float*)d_in[3];
  const float* a2  = (const float*)d_in[4];
  float* out = (float*)d_out;

  char* ws = (char*)d_ws;
  const size_t WT_OFF = 0;
  const size_t HT_OFF = WT_OFF + (size_t)NHEAD * FOUT * FIN * 2;     // 256 KB
  const size_t F1_OFF = HT_OFF + (size_t)NHEAD * FOUT * NROW * 2;    // 4 MB
  const size_t E2_OFF = F1_OFF + (size_t)NHEAD * NROW * 4;           // 128 KB
  const size_t D2_OFF = E2_OFF + (size_t)NHEAD * NROW * 2;           // 64 KB
  const size_t PT_OFF = D2_OFF + (size_t)NHEAD * NROW * 2;           // 64 KB
  // part: [4][NHEAD][NROW][68] f32 = 35.7 MB; total ~40 MB

  __hip_bfloat16* WT = (__hip_bfloat16*)(ws + WT_OFF);
  _Float16* hT = (_Float16*)(ws + HT_OFF);
  float* f1 = (float*)(ws + F1_OFF);
  _Float16* E2h = (_Float16*)(ws + E2_OFF);
  _Float16* D2h = (_Float16*)(ws + D2_OFF);
  float* part = (float*)(ws + PT_OFF);

  wt_build<<<8, 256, 0, stream>>>(W, WT);
  gat_proj<<<NHEAD * (NROW / 64), 256, 0, stream>>>(x, WT, a1, a2, hT, f1, E2h, D2h);
  gat_attn<<<4 * NHEAD * (NROW / 128), 256, 0, stream>>>(adj, hT, f1, E2h, D2h, part);
  gat_comb<<<NROW * NHEAD * FOUT / 4 / 256, 256, 0, stream>>>(part, out, 4);
}